// Round 9
// baseline (180.286 us; speedup 1.0000x reference)
//
#include <hip/hip_runtime.h>
#include <hip/hip_bf16.h>

#define B_SZ 4096
#define DZ   512
#define H_SZ 2048
#define DY   10

// c_k = C(64,k)/64^k  (binomial coefficients of (1+u/64)^64), c0=c1=1
#define C2 0.4921875f
#define C3 0.158935546875f
#define C4 0.037872314453125f
#define C5 ((float)(7624512.0/1073741824.0))
#define C6 ((float)(74974368.0/68719476736.0))

typedef __attribute__((ext_vector_type(8))) __bf16 bf16x8;
typedef __attribute__((ext_vector_type(4))) float  f32x4;
typedef __attribute__((ext_vector_type(8))) unsigned short us8;

__device__ inline unsigned short f2bf(float f) {
    unsigned u = __float_as_uint(f);
    u += 0x7fffu + ((u >> 16) & 1u);   // RTNE
    return (unsigned short)(u >> 16);
}
__device__ inline float bf2f(unsigned short s) {
    return __uint_as_float(((unsigned)s) << 16);
}

union SqSmem {
    struct { unsigned short A[64 * 64]; unsigned short B[64 * 64]; } s; // 16 KB
    float epi[64 * 68];                                                 // 17.4 KB
};

#define MFMA_STEP(acc)                                                        \
    {                                                                         \
        _Pragma("unroll")                                                     \
        for (int ks = 0; ks < 2; ++ks) {                                      \
            bf16x8 af[2], bfr[2];                                             \
            _Pragma("unroll")                                                 \
            for (int i = 0; i < 2; ++i) {                                     \
                int ra = wm + i * 16 + l16, ca = (ks * 4 + quad) ^ (ra & 7);  \
                af[i] = *(const bf16x8*)&sm.s.A[ra * 64 + ca * 8];            \
                int rb = wn + i * 16 + l16, cb = (ks * 4 + quad) ^ (rb & 7);  \
                bfr[i] = *(const bf16x8*)&sm.s.B[rb * 64 + cb * 8];           \
            }                                                                 \
            _Pragma("unroll")                                                 \
            for (int i = 0; i < 2; ++i)                                       \
                _Pragma("unroll")                                             \
                for (int j = 0; j < 2; ++j)                                   \
                    acc[i][j] = __builtin_amdgcn_mfma_f32_16x16x32_bf16(      \
                        af[i], bfr[j], acc[i][j], 0, 0, 0);                   \
        }                                                                     \
    }

#define ACC_TO_EPI(acc)                                                       \
    {                                                                         \
        _Pragma("unroll")                                                     \
        for (int i = 0; i < 2; ++i)                                           \
            _Pragma("unroll")                                                 \
            for (int j = 0; j < 2; ++j)                                       \
                _Pragma("unroll")                                             \
                for (int rr = 0; rr < 4; ++rr)                                \
                    sm.epi[(wm + i * 16 + quad * 4 + rr) * 68 +               \
                           wn + j * 16 + l16] = acc[i][j][rr];                \
        __syncthreads();                                                      \
    }

// ---------------------------------------------------------------------------
// gemm64_mfma: 64x64 tile of (Arows)·(Brows)^T, bf16 sources, K=512 -> sm.epi
// ---------------------------------------------------------------------------
__device__ inline void gemm64_mfma(const unsigned short* __restrict__ Arows,
                                   const unsigned short* __restrict__ Brows,
                                   int m0, int n0, int t, SqSmem& sm) {
    const int lane = t & 63, w = t >> 6, quad = lane >> 4, l16 = lane & 15;
    const int wm = (w & 1) * 32, wn = (w >> 1) * 32;
    f32x4 acc[2][2];
#pragma unroll
    for (int i = 0; i < 2; ++i)
#pragma unroll
        for (int j = 0; j < 2; ++j) acc[i][j] = (f32x4){0.f, 0.f, 0.f, 0.f};
    for (int kt = 0; kt < 8; ++kt) {
#pragma unroll
        for (int c = 0; c < 2; ++c) {
            int idx = c * 256 + t, row = idx >> 3, cc = idx & 7;
            int ccs = cc ^ (row & 7);
            *(us8*)&sm.s.A[row * 64 + ccs * 8] =
                *(const us8*)&Arows[(size_t)(m0 + row) * 512 + kt * 64 + cc * 8];
            *(us8*)&sm.s.B[row * 64 + ccs * 8] =
                *(const us8*)&Brows[(size_t)(n0 + row) * 512 + kt * 64 + cc * 8];
        }
        __syncthreads();
        MFMA_STEP(acc)
        __syncthreads();
    }
    ACC_TO_EPI(acc)
}

// ---------------------------------------------------------------------------
// gemm64_f32src: 64x64 tile of Arows·Bsrc (BOTH fp32 row-major, stride 512),
// staged with inline f2bf; B transposed via scalar scatter (r5/r7-proven).
// ---------------------------------------------------------------------------
__device__ inline void gemm64_f32src(const float* __restrict__ Arows,
                                     const float* __restrict__ Bsrc,
                                     int m0, int n0, int t, SqSmem& sm) {
    const int lane = t & 63, w = t >> 6, quad = lane >> 4, l16 = lane & 15;
    const int wm = (w & 1) * 32, wn = (w >> 1) * 32;
    const int r = t >> 2, cq = t & 3;
    f32x4 acc[2][2];
#pragma unroll
    for (int i = 0; i < 2; ++i)
#pragma unroll
        for (int j = 0; j < 2; ++j) acc[i][j] = (f32x4){0.f, 0.f, 0.f, 0.f};
    for (int kt = 0; kt < 8; ++kt) {
        float va[16];
#pragma unroll
        for (int u = 0; u < 4; ++u) {
            float4 f = *(const float4*)&Arows[(size_t)(m0 + r) * 512 + kt * 64 + cq * 16 + u * 4];
            va[u * 4 + 0] = f.x; va[u * 4 + 1] = f.y;
            va[u * 4 + 2] = f.z; va[u * 4 + 3] = f.w;
        }
#pragma unroll
        for (int j2 = 0; j2 < 2; ++j2) {
            us8 h;
#pragma unroll
            for (int j = 0; j < 8; ++j) h[j] = f2bf(va[j2 * 8 + j]);
            int cc = cq * 2 + j2;
            *(us8*)&sm.s.A[r * 64 + (cc ^ (r & 7)) * 8] = h;
        }
#pragma unroll
        for (int u = 0; u < 4; ++u) {
            float4 f = *(const float4*)&Bsrc[(size_t)(kt * 64 + r) * 512 + n0 + cq * 16 + u * 4];
            float vv[4] = {f.x, f.y, f.z, f.w};
#pragma unroll
            for (int j = 0; j < 4; ++j) {
                int n = cq * 16 + u * 4 + j;
                sm.s.B[n * 64 + ((r >> 3) ^ (n & 7)) * 8 + (r & 7)] = f2bf(vv[j]);
            }
        }
        __syncthreads();
        MFMA_STEP(acc)
        __syncthreads();
    }
    ACC_TO_EPI(acc)
}

__device__ inline void epi_out_bf(unsigned short* __restrict__ dst, int m0,
                                  int n0, int t, SqSmem& sm) {
    const int r = t >> 2, cq = t & 3;
    us8 h0, h1;
#pragma unroll
    for (int j = 0; j < 8; ++j) {
        h0[j] = f2bf(sm.epi[r * 68 + cq * 16 + j]);
        h1[j] = f2bf(sm.epi[r * 68 + cq * 16 + 8 + j]);
    }
    *(us8*)&dst[(size_t)(m0 + r) * 512 + n0 + cq * 16]     = h0;
    *(us8*)&dst[(size_t)(m0 + r) * 512 + n0 + cq * 16 + 8] = h1;
}
__device__ inline void epi_out_bfT(unsigned short* __restrict__ dst, int m0,
                                   int n0, int t, SqSmem& sm) {
    const int cf = t >> 2, rq = t & 3;
    us8 o0, o1;
#pragma unroll
    for (int i = 0; i < 8; ++i) {
        o0[i] = f2bf(sm.epi[(rq * 16 + i) * 68 + cf]);
        o1[i] = f2bf(sm.epi[(rq * 16 + 8 + i) * 68 + cf]);
    }
    *(us8*)&dst[(size_t)(n0 + cf) * 512 + m0 + rq * 16]     = o0;
    *(us8*)&dst[(size_t)(n0 + cf) * 512 + m0 + rq * 16 + 8] = o1;
}

// ===========================================================================
// k_g1 (grid 384): 0..63: A2 = f32src(A,A) -> A2_bf, A2T_bf ;
// 64..127: AT_bf (fp32 LDS transpose) ; 128..383: U1 = f32src(W1,A) -> U1_bf ;
// y = b2 broadcast (all blocks). NO separate conversion kernel.
// ===========================================================================
__global__ __launch_bounds__(256) void k_g1(
    const float* __restrict__ A, const float* __restrict__ W1,
    const float* __restrict__ b2,
    unsigned short* __restrict__ A2_bf, unsigned short* __restrict__ A2T_bf,
    unsigned short* __restrict__ AT_bf, unsigned short* __restrict__ U1_bf,
    float* __restrict__ y) {
    __shared__ SqSmem sm;
    const int b = blockIdx.x, t = threadIdx.x;
    const int gid = b * 256 + t;
    if (gid < B_SZ * DY) y[gid] = b2[gid % 10];

    if (b < 64) {
        const int m0 = (b >> 3) * 64, n0 = (b & 7) * 64;
        gemm64_f32src(A, A, m0, n0, t, sm);
        epi_out_bf(A2_bf, m0, n0, t, sm);
        epi_out_bfT(A2T_bf, m0, n0, t, sm);
    } else if (b < 128) {
        const int bb = b - 64, m0 = (bb >> 3) * 64, n0 = (bb & 7) * 64;
        const int r = t >> 2, cq = t & 3;
#pragma unroll
        for (int u = 0; u < 4; ++u) {
            float4 f = *(const float4*)&A[(size_t)(m0 + r) * 512 + n0 + cq * 16 + u * 4];
            sm.epi[r * 68 + cq * 16 + u * 4 + 0] = f.x;
            sm.epi[r * 68 + cq * 16 + u * 4 + 1] = f.y;
            sm.epi[r * 68 + cq * 16 + u * 4 + 2] = f.z;
            sm.epi[r * 68 + cq * 16 + u * 4 + 3] = f.w;
        }
        __syncthreads();
        epi_out_bfT(AT_bf, m0, n0, t, sm);
    } else {
        const int bb = b - 128, m0 = (bb >> 3) * 64, n0 = (bb & 7) * 64;
        gemm64_f32src(W1, A, m0, n0, t, sm);     // U1 = W1·A
        epi_out_bf(U1_bf, m0, n0, t, sm);
    }
}

// ===========================================================================
// k_g2 (grid 576): 0..63: A3 = A2·A -> A3T_bf ; 64..319: U2 = U1·A ;
// 320..575: U3 = U1·A2
// ===========================================================================
__global__ __launch_bounds__(256) void k_g2(
    const unsigned short* __restrict__ A2_bf,
    const unsigned short* __restrict__ A2T_bf,
    const unsigned short* __restrict__ AT_bf,
    const unsigned short* __restrict__ U1_bf,
    unsigned short* __restrict__ A3T_bf, unsigned short* __restrict__ U2_bf,
    unsigned short* __restrict__ U3_bf) {
    __shared__ SqSmem sm;
    const int b = blockIdx.x, t = threadIdx.x;
    if (b < 64) {
        const int m0 = (b >> 3) * 64, n0 = (b & 7) * 64;
        gemm64_mfma(A2_bf, AT_bf, m0, n0, t, sm);
        epi_out_bfT(A3T_bf, m0, n0, t, sm);
    } else if (b < 320) {
        const int bb = b - 64, m0 = (bb >> 3) * 64, n0 = (bb & 7) * 64;
        gemm64_mfma(U1_bf, AT_bf, m0, n0, t, sm);
        epi_out_bf(U2_bf, m0, n0, t, sm);
    } else {
        const int bb = b - 320, m0 = (bb >> 3) * 64, n0 = (bb & 7) * 64;
        gemm64_mfma(U1_bf, A2T_bf, m0, n0, t, sm);
        epi_out_bf(U3_bf, m0, n0, t, sm);
    }
}

// ===========================================================================
// k_g3 (grid 256): w1f = bf16( W1 + U1 + c2U2 + c3U3
//                              + (c4U1 + c5U2 + c6U3)·A3 )   (r7-proven)
// ===========================================================================
__global__ __launch_bounds__(256) void k_g3(
    const float* __restrict__ W1, const unsigned short* __restrict__ U1_bf,
    const unsigned short* __restrict__ U2_bf,
    const unsigned short* __restrict__ U3_bf,
    const unsigned short* __restrict__ A3T_bf,
    unsigned short* __restrict__ w1f) {
    __shared__ SqSmem sm;
    const int b = blockIdx.x, t = threadIdx.x;
    const int m0 = (b >> 3) * 64, n0 = (b & 7) * 64;
    const int lane = t & 63, w = t >> 6, quad = lane >> 4, l16 = lane & 15;
    const int wm = (w & 1) * 32, wn = (w >> 1) * 32;
    f32x4 acc[2][2];
#pragma unroll
    for (int i = 0; i < 2; ++i)
#pragma unroll
        for (int j = 0; j < 2; ++j) acc[i][j] = (f32x4){0.f, 0.f, 0.f, 0.f};
    for (int kt = 0; kt < 8; ++kt) {
#pragma unroll
        for (int c = 0; c < 2; ++c) {
            int idx = c * 256 + t, row = idx >> 3, cc = idx & 7;
            int ccs = cc ^ (row & 7);
            size_t ga = (size_t)(m0 + row) * 512 + kt * 64 + cc * 8;
            us8 u1 = *(const us8*)&U1_bf[ga];
            us8 u2 = *(const us8*)&U2_bf[ga];
            us8 u3 = *(const us8*)&U3_bf[ga];
            us8 g;
#pragma unroll
            for (int j = 0; j < 8; ++j)
                g[j] = f2bf(C4 * bf2f(u1[j]) + C5 * bf2f(u2[j]) + C6 * bf2f(u3[j]));
            *(us8*)&sm.s.A[row * 64 + ccs * 8] = g;
            *(us8*)&sm.s.B[row * 64 + ccs * 8] =
                *(const us8*)&A3T_bf[(size_t)(n0 + row) * 512 + kt * 64 + cc * 8];
        }
        __syncthreads();
        MFMA_STEP(acc)
        __syncthreads();
    }
    ACC_TO_EPI(acc)
    const int r = t >> 2, cq = t & 3;
    size_t gbase = (size_t)(m0 + r) * 512 + n0 + cq * 16;
    us8 u1a = *(const us8*)&U1_bf[gbase], u1b = *(const us8*)&U1_bf[gbase + 8];
    us8 u2a = *(const us8*)&U2_bf[gbase], u2b = *(const us8*)&U2_bf[gbase + 8];
    us8 u3a = *(const us8*)&U3_bf[gbase], u3b = *(const us8*)&U3_bf[gbase + 8];
    us8 h0, h1;
#pragma unroll
    for (int u = 0; u < 2; ++u) {
        float4 wv = *(const float4*)&W1[gbase + u * 4];
        float4 wv2 = *(const float4*)&W1[gbase + 8 + u * 4];
#pragma unroll
        for (int j = 0; j < 4; ++j) {
            int e = u * 4 + j;
            float wj = (j == 0 ? wv.x : j == 1 ? wv.y : j == 2 ? wv.z : wv.w);
            float wj2 = (j == 0 ? wv2.x : j == 1 ? wv2.y : j == 2 ? wv2.z : wv2.w);
            h0[e] = f2bf(wj + bf2f(u1a[e]) + C2 * bf2f(u2a[e]) +
                         C3 * bf2f(u3a[e]) + sm.epi[r * 68 + cq * 16 + e]);
            h1[e] = f2bf(wj2 + bf2f(u1b[e]) + C2 * bf2f(u2b[e]) +
                         C3 * bf2f(u3b[e]) + sm.epi[r * 68 + cq * 16 + 8 + e]);
        }
    }
    *(us8*)&w1f[gbase]     = h0;
    *(us8*)&w1f[gbase + 8] = h1;
}

// ===========================================================================
// mlp v4: 128x64 tiles, grid (32,32)=1024 blocks (4 blocks/CU), x read fp32
// with inline f2bf staging. h = relu(x@w1f^T + b1); y += h@W2^T (atomicAdd).
// ===========================================================================
union SmemU {
    struct { unsigned short A[128 * 64]; unsigned short B[64 * 64]; } s; // 24 KB
    struct { unsigned short h[64 * 130]; float w2[DY * 68]; } e;         // 19.4 KB
};

__global__ __launch_bounds__(256) void mlp_kernel(
    const float* __restrict__ x,
    const unsigned short* __restrict__ w1f,
    const float* __restrict__ b1, const float* __restrict__ W2,
    float* __restrict__ y) {
    __shared__ SmemU sm;
    const int t    = threadIdx.x;
    const int lane = t & 63, w = t >> 6;
    const int quad = lane >> 4, l16 = lane & 15;
    const int wm = (w >> 1) * 64, wn = (w & 1) * 32;
    const int m0g = blockIdx.x * 128, n0g = blockIdx.y * 64;

    f32x4 acc[4][2];
#pragma unroll
    for (int i = 0; i < 4; ++i)
#pragma unroll
        for (int j = 0; j < 2; ++j) acc[i][j] = (f32x4){0.f, 0.f, 0.f, 0.f};

    for (int kt = 0; kt < 8; ++kt) {
        // A: 128x64 from fp32 x, inline convert (1024 chunks)
#pragma unroll
        for (int c = 0; c < 4; ++c) {
            int idx = c * 256 + t, row = idx >> 3, cc = idx & 7;
            int ccs = cc ^ (row & 7);
            const float* gp = &x[(size_t)(m0g + row) * 512 + kt * 64 + cc * 8];
            float4 f0 = *(const float4*)gp;
            float4 f1 = *(const float4*)(gp + 4);
            us8 o;
            o[0] = f2bf(f0.x); o[1] = f2bf(f0.y); o[2] = f2bf(f0.z); o[3] = f2bf(f0.w);
            o[4] = f2bf(f1.x); o[5] = f2bf(f1.y); o[6] = f2bf(f1.z); o[7] = f2bf(f1.w);
            *(us8*)&sm.s.A[row * 64 + ccs * 8] = o;
        }
        // B: 64x64 bf16 from w1f (512 chunks)
#pragma unroll
        for (int c = 0; c < 2; ++c) {
            int idx = c * 256 + t, row = idx >> 3, cc = idx & 7;
            int ccs = cc ^ (row & 7);
            *(us8*)&sm.s.B[row * 64 + ccs * 8] =
                *(const us8*)&w1f[(size_t)(n0g + row) * 512 + kt * 64 + cc * 8];
        }
        __syncthreads();
#pragma unroll
        for (int ks = 0; ks < 2; ++ks) {
            bf16x8 af[4], bfr[2];
#pragma unroll
            for (int i = 0; i < 4; ++i) {
                int ra = wm + i * 16 + l16, ca = (ks * 4 + quad) ^ (ra & 7);
                af[i] = *(const bf16x8*)&sm.s.A[ra * 64 + ca * 8];
            }
#pragma unroll
            for (int j = 0; j < 2; ++j) {
                int rb = wn + j * 16 + l16, cb = (ks * 4 + quad) ^ (rb & 7);
                bfr[j] = *(const bf16x8*)&sm.s.B[rb * 64 + cb * 8];
            }
#pragma unroll
            for (int i = 0; i < 4; ++i)
#pragma unroll
                for (int j = 0; j < 2; ++j)
                    acc[i][j] = __builtin_amdgcn_mfma_f32_16x16x32_bf16(
                        af[i], bfr[j], acc[i][j], 0, 0, 0);
        }
        __syncthreads();
    }

    // ---- epilogue: bias+relu -> LDS h (n-major), then y += h @ W2^T ----
    float bias[2];
#pragma unroll
    for (int j = 0; j < 2; ++j) bias[j] = b1[n0g + wn + j * 16 + l16];
#pragma unroll
    for (int i = 0; i < 4; ++i)
#pragma unroll
        for (int j = 0; j < 2; ++j)
#pragma unroll
            for (int r = 0; r < 4; ++r) {
                float h = acc[i][j][r] + bias[j];
                h = h > 0.f ? h : 0.f;
                sm.e.h[(wn + j * 16 + l16) * 130 + (wm + i * 16 + quad * 4 + r)] = f2bf(h);
            }
    for (int i = t; i < DY * 64; i += 256) {
        int d = i >> 6, n = i & 63;
        sm.e.w2[d * 68 + n] = W2[(size_t)d * H_SZ + n0g + n];
    }
    __syncthreads();
    {
        int m = t >> 1, dg = t & 1;
        float s0 = 0.f, s1 = 0.f, s2 = 0.f, s3 = 0.f, s4 = 0.f;
        const float* wrow = &sm.e.w2[dg * 5 * 68];
#pragma unroll 4
        for (int n = 0; n < 64; ++n) {
            float h = bf2f(sm.e.h[n * 130 + m]);
            s0 += h * wrow[n];
            s1 += h * wrow[68 + n];
            s2 += h * wrow[136 + n];
            s3 += h * wrow[204 + n];
            s4 += h * wrow[272 + n];
        }
        float* yp = &y[(size_t)(m0g + m) * DY + dg * 5];
        atomicAdd(yp + 0, s0);
        atomicAdd(yp + 1, s1);
        atomicAdd(yp + 2, s2);
        atomicAdd(yp + 3, s3);
        atomicAdd(yp + 4, s4);
    }
}

// ===========================================================================
extern "C" void kernel_launch(void* const* d_in, const int* in_sizes, int n_in,
                              void* d_out, int out_size, void* d_ws, size_t ws_size,
                              hipStream_t stream) {
    const float* x  = (const float*)d_in[0];
    const float* A  = (const float*)d_in[1];
    const float* W1 = (const float*)d_in[2];
    const float* b1 = (const float*)d_in[3];
    const float* W2 = (const float*)d_in[4];
    const float* b2 = (const float*)d_in[5];
    float* y = (float*)d_out;

    char* ws = (char*)d_ws;
    const size_t HMB = 512u * 1024, MB = 1u << 20;
    unsigned short* AT_bf  = (unsigned short*)(ws);
    unsigned short* A2_bf  = (unsigned short*)(ws + 1 * HMB);
    unsigned short* A2T_bf = (unsigned short*)(ws + 2 * HMB);
    unsigned short* A3T_bf = (unsigned short*)(ws + 3 * HMB);
    unsigned short* U1_bf  = (unsigned short*)(ws + 2 * MB);   // 2 MB
    unsigned short* U2_bf  = (unsigned short*)(ws + 4 * MB);   // 2 MB
    unsigned short* U3_bf  = (unsigned short*)(ws + 6 * MB);   // 2 MB
    unsigned short* w1f    = (unsigned short*)(ws + 8 * MB);   // 2 MB

    k_g1<<<384, 256, 0, stream>>>(A, W1, b2, A2_bf, A2T_bf, AT_bf, U1_bf, y);
    k_g2<<<576, 256, 0, stream>>>(A2_bf, A2T_bf, AT_bf, U1_bf, A3T_bf, U2_bf,
                                  U3_bf);
    k_g3<<<256, 256, 0, stream>>>(W1, U1_bf, U2_bf, U3_bf, A3T_bf, w1f);
    mlp_kernel<<<dim3(32, 32), dim3(256), 0, stream>>>(x, w1f, b1, W2, y);
}

// Round 11
// 142.060 us; speedup vs baseline: 1.2691x; 1.2691x over previous
//
#include <hip/hip_runtime.h>
#include <hip/hip_bf16.h>

#define B_SZ 4096
#define DZ   512
#define H_SZ 2048
#define DY   10

// c_k = C(64,k)/64^k  (binomial coefficients of (1+u/64)^64), c0=c1=1
#define C2 0.4921875f
#define C3 0.158935546875f
#define C4 0.037872314453125f
#define C5 ((float)(7624512.0/1073741824.0))
#define C6 ((float)(74974368.0/68719476736.0))

typedef __attribute__((ext_vector_type(8))) __bf16 bf16x8;
typedef __attribute__((ext_vector_type(4))) float  f32x4;
typedef __attribute__((ext_vector_type(8))) unsigned short us8;

__device__ inline unsigned short f2bf(float f) {
    unsigned u = __float_as_uint(f);
    u += 0x7fffu + ((u >> 16) & 1u);   // RTNE
    return (unsigned short)(u >> 16);
}
__device__ inline float bf2f(unsigned short s) {
    return __uint_as_float(((unsigned)s) << 16);
}

union SqSmem {
    struct { unsigned short A[64 * 64]; unsigned short B[64 * 64]; } s; // 16 KB
    float epi[64 * 68];                                                 // 17.4 KB
};

#define MFMA_STEP(acc)                                                        \
    {                                                                         \
        _Pragma("unroll")                                                     \
        for (int ks = 0; ks < 2; ++ks) {                                      \
            bf16x8 af[2], bfr[2];                                             \
            _Pragma("unroll")                                                 \
            for (int i = 0; i < 2; ++i) {                                     \
                int ra = wm + i * 16 + l16, ca = (ks * 4 + quad) ^ (ra & 7);  \
                af[i] = *(const bf16x8*)&sm.s.A[ra * 64 + ca * 8];            \
                int rb = wn + i * 16 + l16, cb = (ks * 4 + quad) ^ (rb & 7);  \
                bfr[i] = *(const bf16x8*)&sm.s.B[rb * 64 + cb * 8];           \
            }                                                                 \
            _Pragma("unroll")                                                 \
            for (int i = 0; i < 2; ++i)                                       \
                _Pragma("unroll")                                             \
                for (int j = 0; j < 2; ++j)                                   \
                    acc[i][j] = __builtin_amdgcn_mfma_f32_16x16x32_bf16(      \
                        af[i], bfr[j], acc[i][j], 0, 0, 0);                   \
        }                                                                     \
    }

#define ACC_TO_EPI(acc)                                                       \
    {                                                                         \
        _Pragma("unroll")                                                     \
        for (int i = 0; i < 2; ++i)                                           \
            _Pragma("unroll")                                                 \
            for (int j = 0; j < 2; ++j)                                       \
                _Pragma("unroll")                                             \
                for (int rr = 0; rr < 4; ++rr)                                \
                    sm.epi[(wm + i * 16 + quad * 4 + rr) * 68 +               \
                           wn + j * 16 + l16] = acc[i][j][rr];                \
        __syncthreads();                                                      \
    }

// ---------------------------------------------------------------------------
// gemm64_mfma: 64x64 tile of (Arows)·(Brows)^T, bf16 sources, K=512 -> sm.epi
// ---------------------------------------------------------------------------
__device__ inline void gemm64_mfma(const unsigned short* __restrict__ Arows,
                                   const unsigned short* __restrict__ Brows,
                                   int m0, int n0, int t, SqSmem& sm) {
    const int lane = t & 63, w = t >> 6, quad = lane >> 4, l16 = lane & 15;
    const int wm = (w & 1) * 32, wn = (w >> 1) * 32;
    f32x4 acc[2][2];
#pragma unroll
    for (int i = 0; i < 2; ++i)
#pragma unroll
        for (int j = 0; j < 2; ++j) acc[i][j] = (f32x4){0.f, 0.f, 0.f, 0.f};
    for (int kt = 0; kt < 8; ++kt) {
#pragma unroll
        for (int c = 0; c < 2; ++c) {
            int idx = c * 256 + t, row = idx >> 3, cc = idx & 7;
            int ccs = cc ^ (row & 7);
            *(us8*)&sm.s.A[row * 64 + ccs * 8] =
                *(const us8*)&Arows[(size_t)(m0 + row) * 512 + kt * 64 + cc * 8];
            *(us8*)&sm.s.B[row * 64 + ccs * 8] =
                *(const us8*)&Brows[(size_t)(n0 + row) * 512 + kt * 64 + cc * 8];
        }
        __syncthreads();
        MFMA_STEP(acc)
        __syncthreads();
    }
    ACC_TO_EPI(acc)
}

// ---------------------------------------------------------------------------
// gemm64_f32src: 64x64 tile of Arows·Bsrc (BOTH fp32 row-major, stride 512),
// staged with inline f2bf; B transposed via scalar scatter (r5/r7-proven).
// ---------------------------------------------------------------------------
__device__ inline void gemm64_f32src(const float* __restrict__ Arows,
                                     const float* __restrict__ Bsrc,
                                     int m0, int n0, int t, SqSmem& sm) {
    const int lane = t & 63, w = t >> 6, quad = lane >> 4, l16 = lane & 15;
    const int wm = (w & 1) * 32, wn = (w >> 1) * 32;
    const int r = t >> 2, cq = t & 3;
    f32x4 acc[2][2];
#pragma unroll
    for (int i = 0; i < 2; ++i)
#pragma unroll
        for (int j = 0; j < 2; ++j) acc[i][j] = (f32x4){0.f, 0.f, 0.f, 0.f};
    for (int kt = 0; kt < 8; ++kt) {
        float va[16];
#pragma unroll
        for (int u = 0; u < 4; ++u) {
            float4 f = *(const float4*)&Arows[(size_t)(m0 + r) * 512 + kt * 64 + cq * 16 + u * 4];
            va[u * 4 + 0] = f.x; va[u * 4 + 1] = f.y;
            va[u * 4 + 2] = f.z; va[u * 4 + 3] = f.w;
        }
#pragma unroll
        for (int j2 = 0; j2 < 2; ++j2) {
            us8 h;
#pragma unroll
            for (int j = 0; j < 8; ++j) h[j] = f2bf(va[j2 * 8 + j]);
            int cc = cq * 2 + j2;
            *(us8*)&sm.s.A[r * 64 + (cc ^ (r & 7)) * 8] = h;
        }
#pragma unroll
        for (int u = 0; u < 4; ++u) {
            float4 f = *(const float4*)&Bsrc[(size_t)(kt * 64 + r) * 512 + n0 + cq * 16 + u * 4];
            float vv[4] = {f.x, f.y, f.z, f.w};
#pragma unroll
            for (int j = 0; j < 4; ++j) {
                int n = cq * 16 + u * 4 + j;
                sm.s.B[n * 64 + ((r >> 3) ^ (n & 7)) * 8 + (r & 7)] = f2bf(vv[j]);
            }
        }
        __syncthreads();
        MFMA_STEP(acc)
        __syncthreads();
    }
    ACC_TO_EPI(acc)
}

__device__ inline void epi_out_bf(unsigned short* __restrict__ dst, int m0,
                                  int n0, int t, SqSmem& sm) {
    const int r = t >> 2, cq = t & 3;
    us8 h0, h1;
#pragma unroll
    for (int j = 0; j < 8; ++j) {
        h0[j] = f2bf(sm.epi[r * 68 + cq * 16 + j]);
        h1[j] = f2bf(sm.epi[r * 68 + cq * 16 + 8 + j]);
    }
    *(us8*)&dst[(size_t)(m0 + r) * 512 + n0 + cq * 16]     = h0;
    *(us8*)&dst[(size_t)(m0 + r) * 512 + n0 + cq * 16 + 8] = h1;
}
__device__ inline void epi_out_bfT(unsigned short* __restrict__ dst, int m0,
                                   int n0, int t, SqSmem& sm) {
    const int cf = t >> 2, rq = t & 3;
    us8 o0, o1;
#pragma unroll
    for (int i = 0; i < 8; ++i) {
        o0[i] = f2bf(sm.epi[(rq * 16 + i) * 68 + cf]);
        o1[i] = f2bf(sm.epi[(rq * 16 + 8 + i) * 68 + cf]);
    }
    *(us8*)&dst[(size_t)(n0 + cf) * 512 + m0 + rq * 16]     = o0;
    *(us8*)&dst[(size_t)(n0 + cf) * 512 + m0 + rq * 16 + 8] = o1;
}

// ===========================================================================
// k_s1 (grid 384): x->bf16; y=b2; 0..63: A2 = f32src(A,A); 64..127: AT_bf;
// 128..383: U1 = f32src(W1,A)    (r7-proven)
// ===========================================================================
__global__ __launch_bounds__(256) void k_s1(
    const float* __restrict__ A, const float* __restrict__ x,
    const float* __restrict__ W1, const float* __restrict__ b2,
    unsigned short* __restrict__ A2_bf, unsigned short* __restrict__ A2T_bf,
    unsigned short* __restrict__ AT_bf, unsigned short* __restrict__ U1_bf,
    unsigned short* __restrict__ x_bf, float* __restrict__ y) {
    __shared__ SqSmem sm;
    const int b = blockIdx.x, t = threadIdx.x;
    const int gid = b * 256 + t;                 // 0 .. 98303

    const float4* x4 = (const float4*)x;
#pragma unroll
    for (int i = 0; i < 3; ++i) {
        int id = gid + i * 98304;
        if (id < 262144) {
            float4 v0 = x4[(size_t)id * 2], v1 = x4[(size_t)id * 2 + 1];
            us8 o;
            o[0] = f2bf(v0.x); o[1] = f2bf(v0.y); o[2] = f2bf(v0.z); o[3] = f2bf(v0.w);
            o[4] = f2bf(v1.x); o[5] = f2bf(v1.y); o[6] = f2bf(v1.z); o[7] = f2bf(v1.w);
            *(us8*)&x_bf[(size_t)id * 8] = o;
        }
    }
    if (gid < B_SZ * DY) y[gid] = b2[gid % 10];

    if (b < 64) {
        const int m0 = (b >> 3) * 64, n0 = (b & 7) * 64;
        gemm64_f32src(A, A, m0, n0, t, sm);
        epi_out_bf(A2_bf, m0, n0, t, sm);
        epi_out_bfT(A2T_bf, m0, n0, t, sm);
    } else if (b < 128) {
        const int bb = b - 64, m0 = (bb >> 3) * 64, n0 = (bb & 7) * 64;
        const int r = t >> 2, cq = t & 3;
#pragma unroll
        for (int u = 0; u < 4; ++u) {
            float4 f = *(const float4*)&A[(size_t)(m0 + r) * 512 + n0 + cq * 16 + u * 4];
            sm.epi[r * 68 + cq * 16 + u * 4 + 0] = f.x;
            sm.epi[r * 68 + cq * 16 + u * 4 + 1] = f.y;
            sm.epi[r * 68 + cq * 16 + u * 4 + 2] = f.z;
            sm.epi[r * 68 + cq * 16 + u * 4 + 3] = f.w;
        }
        __syncthreads();
        epi_out_bfT(AT_bf, m0, n0, t, sm);
    } else {
        const int bb = b - 128, m0 = (bb >> 3) * 64, n0 = (bb & 7) * 64;
        gemm64_f32src(W1, A, m0, n0, t, sm);     // U1 = W1·A
        epi_out_bf(U1_bf, m0, n0, t, sm);
    }
}

// ===========================================================================
// k_s2 (grid 576): 0..63: A3 = A2·A -> A3T_bf ; 64..319: U2 = U1·A ;
// 320..575: U3 = U1·A2    (r7-proven)
// ===========================================================================
__global__ __launch_bounds__(256) void k_s2(
    const unsigned short* __restrict__ A2_bf,
    const unsigned short* __restrict__ A2T_bf,
    const unsigned short* __restrict__ AT_bf,
    const unsigned short* __restrict__ U1_bf,
    unsigned short* __restrict__ A3T_bf, unsigned short* __restrict__ U2_bf,
    unsigned short* __restrict__ U3_bf) {
    __shared__ SqSmem sm;
    const int b = blockIdx.x, t = threadIdx.x;
    if (b < 64) {
        const int m0 = (b >> 3) * 64, n0 = (b & 7) * 64;
        gemm64_mfma(A2_bf, AT_bf, m0, n0, t, sm);
        epi_out_bfT(A3T_bf, m0, n0, t, sm);
    } else if (b < 320) {
        const int bb = b - 64, m0 = (bb >> 3) * 64, n0 = (bb & 7) * 64;
        gemm64_mfma(U1_bf, AT_bf, m0, n0, t, sm);
        epi_out_bf(U2_bf, m0, n0, t, sm);
    } else {
        const int bb = b - 320, m0 = (bb >> 3) * 64, n0 = (bb & 7) * 64;
        gemm64_mfma(U1_bf, A2T_bf, m0, n0, t, sm);
        epi_out_bf(U3_bf, m0, n0, t, sm);
    }
}

// ===========================================================================
// k_s3 (grid 256): w1f = bf16( W1 + U1 + c2U2 + c3U3
//                              + (c4U1 + c5U2 + c6U3)·A3 )   (r7-proven)
// ===========================================================================
__global__ __launch_bounds__(256) void k_s3(
    const float* __restrict__ W1, const unsigned short* __restrict__ U1_bf,
    const unsigned short* __restrict__ U2_bf,
    const unsigned short* __restrict__ U3_bf,
    const unsigned short* __restrict__ A3T_bf,
    unsigned short* __restrict__ w1f) {
    __shared__ SqSmem sm;
    const int b = blockIdx.x, t = threadIdx.x;
    const int m0 = (b >> 3) * 64, n0 = (b & 7) * 64;
    const int lane = t & 63, w = t >> 6, quad = lane >> 4, l16 = lane & 15;
    const int wm = (w & 1) * 32, wn = (w >> 1) * 32;
    f32x4 acc[2][2];
#pragma unroll
    for (int i = 0; i < 2; ++i)
#pragma unroll
        for (int j = 0; j < 2; ++j) acc[i][j] = (f32x4){0.f, 0.f, 0.f, 0.f};
    for (int kt = 0; kt < 8; ++kt) {
#pragma unroll
        for (int c = 0; c < 2; ++c) {
            int idx = c * 256 + t, row = idx >> 3, cc = idx & 7;
            int ccs = cc ^ (row & 7);
            size_t ga = (size_t)(m0 + row) * 512 + kt * 64 + cc * 8;
            us8 u1 = *(const us8*)&U1_bf[ga];
            us8 u2 = *(const us8*)&U2_bf[ga];
            us8 u3 = *(const us8*)&U3_bf[ga];
            us8 g;
#pragma unroll
            for (int j = 0; j < 8; ++j)
                g[j] = f2bf(C4 * bf2f(u1[j]) + C5 * bf2f(u2[j]) + C6 * bf2f(u3[j]));
            *(us8*)&sm.s.A[row * 64 + ccs * 8] = g;
            *(us8*)&sm.s.B[row * 64 + ccs * 8] =
                *(const us8*)&A3T_bf[(size_t)(n0 + row) * 512 + kt * 64 + cc * 8];
        }
        __syncthreads();
        MFMA_STEP(acc)
        __syncthreads();
    }
    ACC_TO_EPI(acc)
    const int r = t >> 2, cq = t & 3;
    size_t gbase = (size_t)(m0 + r) * 512 + n0 + cq * 16;
    us8 u1a = *(const us8*)&U1_bf[gbase], u1b = *(const us8*)&U1_bf[gbase + 8];
    us8 u2a = *(const us8*)&U2_bf[gbase], u2b = *(const us8*)&U2_bf[gbase + 8];
    us8 u3a = *(const us8*)&U3_bf[gbase], u3b = *(const us8*)&U3_bf[gbase + 8];
    us8 h0, h1;
#pragma unroll
    for (int u = 0; u < 2; ++u) {
        float4 wv = *(const float4*)&W1[gbase + u * 4];
        float4 wv2 = *(const float4*)&W1[gbase + 8 + u * 4];
#pragma unroll
        for (int j = 0; j < 4; ++j) {
            int e = u * 4 + j;
            float wj = (j == 0 ? wv.x : j == 1 ? wv.y : j == 2 ? wv.z : wv.w);
            float wj2 = (j == 0 ? wv2.x : j == 1 ? wv2.y : j == 2 ? wv2.z : wv2.w);
            h0[e] = f2bf(wj + bf2f(u1a[e]) + C2 * bf2f(u2a[e]) +
                         C3 * bf2f(u3a[e]) + sm.epi[r * 68 + cq * 16 + e]);
            h1[e] = f2bf(wj2 + bf2f(u1b[e]) + C2 * bf2f(u2b[e]) +
                         C3 * bf2f(u3b[e]) + sm.epi[r * 68 + cq * 16 + 8 + e]);
        }
    }
    *(us8*)&w1f[gbase]     = h0;
    *(us8*)&w1f[gbase + 8] = h1;
}

// ===========================================================================
// mlp v6: EXACT r7 K-loop (single-buffered, 2 barriers, proven 45 µs) +
// MFMA epilogue only: h -> LDS m-major (stride 136), each wave owns a 32-row
// m-slice and chains 4 MFMAs over k-chunks; 1 atomic per (m,d) per block.
// LDS: max(32 KB staging, 34.8 KB h) = 34.8 KB.
// ===========================================================================
union SmemU {
    struct { unsigned short A[128 * 64]; unsigned short B[128 * 64]; } s; // 32 KB
    struct { unsigned short h[128 * 136]; } e;                            // 34.8 KB
};

__global__ __launch_bounds__(256, 2) void mlp_kernel(
    const unsigned short* __restrict__ x_bf,
    const unsigned short* __restrict__ w1f,
    const float* __restrict__ b1, const float* __restrict__ W2,
    float* __restrict__ y) {
    __shared__ SmemU sm;
    const int t    = threadIdx.x;
    const int lane = t & 63, w = t >> 6;
    const int quad = lane >> 4, l16 = lane & 15;
    const int wm = (w & 1) * 64, wn = (w >> 1) * 64;
    const int m0g = blockIdx.x * 128, n0g = blockIdx.y * 128;

    f32x4 acc[4][4];
#pragma unroll
    for (int i = 0; i < 4; ++i)
#pragma unroll
        for (int j = 0; j < 4; ++j) acc[i][j] = (f32x4){0.f, 0.f, 0.f, 0.f};

    for (int kt = 0; kt < 8; ++kt) {
#pragma unroll
        for (int c = 0; c < 4; ++c) {
            int idx = c * 256 + t;
            int row = idx >> 3, cc = idx & 7;
            int ccs = cc ^ (row & 7);
            us8 va = *(const us8*)&x_bf[(size_t)(m0g + row) * 512 + kt * 64 + cc * 8];
            *(us8*)&sm.s.A[row * 64 + ccs * 8] = va;
            us8 vb = *(const us8*)&w1f[(size_t)(n0g + row) * 512 + kt * 64 + cc * 8];
            *(us8*)&sm.s.B[row * 64 + ccs * 8] = vb;
        }
        __syncthreads();
#pragma unroll
        for (int ks = 0; ks < 2; ++ks) {
            bf16x8 af[4], bfr[4];
#pragma unroll
            for (int i = 0; i < 4; ++i) {
                int ra = wm + i * 16 + l16;
                int rb = wn + i * 16 + l16;
                int ca = (ks * 4 + quad) ^ (ra & 7);
                int cb = (ks * 4 + quad) ^ (rb & 7);
                af[i]  = *(const bf16x8*)&sm.s.A[ra * 64 + ca * 8];
                bfr[i] = *(const bf16x8*)&sm.s.B[rb * 64 + cb * 8];
            }
#pragma unroll
            for (int i = 0; i < 4; ++i)
#pragma unroll
                for (int j = 0; j < 4; ++j)
                    acc[i][j] = __builtin_amdgcn_mfma_f32_16x16x32_bf16(
                        af[i], bfr[j], acc[i][j], 0, 0, 0);
        }
        __syncthreads();
    }

    // ---- epilogue: bias + relu -> LDS h (m-major, stride 136, 16B rows) ----
    float bias[4];
#pragma unroll
    for (int j = 0; j < 4; ++j) bias[j] = b1[n0g + wn + j * 16 + l16];
#pragma unroll
    for (int i = 0; i < 4; ++i)
#pragma unroll
        for (int j = 0; j < 4; ++j)
#pragma unroll
            for (int r = 0; r < 4; ++r) {
                float h = acc[i][j][r] + bias[j];
                h = h > 0.f ? h : 0.f;
                sm.e.h[(wm + i * 16 + quad * 4 + r) * 136 + wn + j * 16 + l16] = f2bf(h);
            }
    __syncthreads();

    // ---- y += h @ W2^T via MFMA: wave w owns m-rows [w*32, w*32+32) ----
    {
        bf16x8 wfrag[4];
#pragma unroll
        for (int kc = 0; kc < 4; ++kc) {
            us8 wb;
            if (l16 < DY) {
                const float* wp = &W2[(size_t)l16 * H_SZ + n0g + kc * 32 + quad * 8];
#pragma unroll
                for (int j = 0; j < 8; ++j) wb[j] = f2bf(wp[j]);
            } else {
#pragma unroll
                for (int j = 0; j < 8; ++j) wb[j] = 0;
            }
            wfrag[kc] = *(bf16x8*)&wb;
        }
#pragma unroll
        for (int i2 = 0; i2 < 2; ++i2) {
            f32x4 ay = (f32x4){0.f, 0.f, 0.f, 0.f};
            const int mrow = w * 32 + i2 * 16;
#pragma unroll
            for (int kc = 0; kc < 4; ++kc) {
                bf16x8 af = *(const bf16x8*)&sm.e.h[(mrow + l16) * 136 + kc * 32 + quad * 8];
                ay = __builtin_amdgcn_mfma_f32_16x16x32_bf16(af, wfrag[kc], ay, 0, 0, 0);
            }
            if (l16 < DY) {
#pragma unroll
                for (int r = 0; r < 4; ++r)
                    atomicAdd(&y[(size_t)(m0g + mrow + quad * 4 + r) * DY + l16],
                              ay[r]);
            }
        }
    }
}

// ===========================================================================
extern "C" void kernel_launch(void* const* d_in, const int* in_sizes, int n_in,
                              void* d_out, int out_size, void* d_ws, size_t ws_size,
                              hipStream_t stream) {
    const float* x  = (const float*)d_in[0];
    const float* A  = (const float*)d_in[1];
    const float* W1 = (const float*)d_in[2];
    const float* b1 = (const float*)d_in[3];
    const float* W2 = (const float*)d_in[4];
    const float* b2 = (const float*)d_in[5];
    float* y = (float*)d_out;

    char* ws = (char*)d_ws;
    const size_t HMB = 512u * 1024, MB = 1u << 20;
    unsigned short* AT_bf  = (unsigned short*)(ws);
    unsigned short* A2_bf  = (unsigned short*)(ws + 1 * HMB);
    unsigned short* A2T_bf = (unsigned short*)(ws + 2 * HMB);
    unsigned short* A3T_bf = (unsigned short*)(ws + 3 * HMB);
    unsigned short* U1_bf  = (unsigned short*)(ws + 2 * MB);   // 2 MB
    unsigned short* U2_bf  = (unsigned short*)(ws + 4 * MB);   // 2 MB
    unsigned short* U3_bf  = (unsigned short*)(ws + 6 * MB);   // 2 MB
    unsigned short* w1f    = (unsigned short*)(ws + 8 * MB);   // 2 MB
    unsigned short* x_bf   = (unsigned short*)(ws + 10 * MB);  // 4 MB

    k_s1<<<384, 256, 0, stream>>>(A, x, W1, b2, A2_bf, A2T_bf, AT_bf, U1_bf,
                                  x_bf, y);
    k_s2<<<576, 256, 0, stream>>>(A2_bf, A2T_bf, AT_bf, U1_bf, A3T_bf, U2_bf,
                                  U3_bf);
    k_s3<<<256, 256, 0, stream>>>(W1, U1_bf, U2_bf, U3_bf, A3T_bf, w1f);
    mlp_kernel<<<dim3(32, 16), dim3(256), 0, stream>>>(x_bf, w1f, b1, W2, y);
}

// Round 12
// 140.996 us; speedup vs baseline: 1.2787x; 1.0075x over previous
//
#include <hip/hip_runtime.h>
#include <hip/hip_bf16.h>

#define B_SZ 4096
#define DZ   512
#define H_SZ 2048
#define DY   10

// c_k = C(64,k)/64^k  (binomial coefficients of (1+u/64)^64), c0=c1=1
#define C2 0.4921875f
#define C3 0.158935546875f
#define C4 0.037872314453125f
#define C5 ((float)(7624512.0/1073741824.0))
#define C6 ((float)(74974368.0/68719476736.0))

typedef __attribute__((ext_vector_type(8))) __bf16 bf16x8;
typedef __attribute__((ext_vector_type(4))) float  f32x4;
typedef __attribute__((ext_vector_type(8))) unsigned short us8;

__device__ inline unsigned short f2bf(float f) {
    unsigned u = __float_as_uint(f);
    u += 0x7fffu + ((u >> 16) & 1u);   // RTNE
    return (unsigned short)(u >> 16);
}
__device__ inline float bf2f(unsigned short s) {
    return __uint_as_float(((unsigned)s) << 16);
}

union SqSmem {
    struct { unsigned short A[64 * 64]; unsigned short B[64 * 64]; } s; // 16 KB
    float epi[64 * 68];                                                 // 17.4 KB
};

#define MFMA_STEP(acc)                                                        \
    {                                                                         \
        _Pragma("unroll")                                                     \
        for (int ks = 0; ks < 2; ++ks) {                                      \
            bf16x8 af[2], bfr[2];                                             \
            _Pragma("unroll")                                                 \
            for (int i = 0; i < 2; ++i) {                                     \
                int ra = wm + i * 16 + l16, ca = (ks * 4 + quad) ^ (ra & 7);  \
                af[i] = *(const bf16x8*)&sm.s.A[ra * 64 + ca * 8];            \
                int rb = wn + i * 16 + l16, cb = (ks * 4 + quad) ^ (rb & 7);  \
                bfr[i] = *(const bf16x8*)&sm.s.B[rb * 64 + cb * 8];           \
            }                                                                 \
            _Pragma("unroll")                                                 \
            for (int i = 0; i < 2; ++i)                                       \
                _Pragma("unroll")                                             \
                for (int j = 0; j < 2; ++j)                                   \
                    acc[i][j] = __builtin_amdgcn_mfma_f32_16x16x32_bf16(      \
                        af[i], bfr[j], acc[i][j], 0, 0, 0);                   \
        }                                                                     \
    }

#define ACC_TO_EPI(acc)                                                       \
    {                                                                         \
        _Pragma("unroll")                                                     \
        for (int i = 0; i < 2; ++i)                                           \
            _Pragma("unroll")                                                 \
            for (int j = 0; j < 2; ++j)                                       \
                _Pragma("unroll")                                             \
                for (int rr = 0; rr < 4; ++rr)                                \
                    sm.epi[(wm + i * 16 + quad * 4 + rr) * 68 +               \
                           wn + j * 16 + l16] = acc[i][j][rr];                \
        __syncthreads();                                                      \
    }

// ---------------------------------------------------------------------------
// gemm64_mfma: 64x64 tile of (Arows)·(Brows)^T, bf16 sources, K=512 -> sm.epi
// ---------------------------------------------------------------------------
__device__ inline void gemm64_mfma(const unsigned short* __restrict__ Arows,
                                   const unsigned short* __restrict__ Brows,
                                   int m0, int n0, int t, SqSmem& sm) {
    const int lane = t & 63, w = t >> 6, quad = lane >> 4, l16 = lane & 15;
    const int wm = (w & 1) * 32, wn = (w >> 1) * 32;
    f32x4 acc[2][2];
#pragma unroll
    for (int i = 0; i < 2; ++i)
#pragma unroll
        for (int j = 0; j < 2; ++j) acc[i][j] = (f32x4){0.f, 0.f, 0.f, 0.f};
    for (int kt = 0; kt < 8; ++kt) {
#pragma unroll
        for (int c = 0; c < 2; ++c) {
            int idx = c * 256 + t, row = idx >> 3, cc = idx & 7;
            int ccs = cc ^ (row & 7);
            *(us8*)&sm.s.A[row * 64 + ccs * 8] =
                *(const us8*)&Arows[(size_t)(m0 + row) * 512 + kt * 64 + cc * 8];
            *(us8*)&sm.s.B[row * 64 + ccs * 8] =
                *(const us8*)&Brows[(size_t)(n0 + row) * 512 + kt * 64 + cc * 8];
        }
        __syncthreads();
        MFMA_STEP(acc)
        __syncthreads();
    }
    ACC_TO_EPI(acc)
}

// ---------------------------------------------------------------------------
// gemm64_f32src: 64x64 tile of Arows·Bsrc (BOTH fp32 row-major, stride 512),
// staged with inline f2bf; B transposed via scalar scatter (r5/r7-proven).
// ---------------------------------------------------------------------------
__device__ inline void gemm64_f32src(const float* __restrict__ Arows,
                                     const float* __restrict__ Bsrc,
                                     int m0, int n0, int t, SqSmem& sm) {
    const int lane = t & 63, w = t >> 6, quad = lane >> 4, l16 = lane & 15;
    const int wm = (w & 1) * 32, wn = (w >> 1) * 32;
    const int r = t >> 2, cq = t & 3;
    f32x4 acc[2][2];
#pragma unroll
    for (int i = 0; i < 2; ++i)
#pragma unroll
        for (int j = 0; j < 2; ++j) acc[i][j] = (f32x4){0.f, 0.f, 0.f, 0.f};
    for (int kt = 0; kt < 8; ++kt) {
        float va[16];
#pragma unroll
        for (int u = 0; u < 4; ++u) {
            float4 f = *(const float4*)&Arows[(size_t)(m0 + r) * 512 + kt * 64 + cq * 16 + u * 4];
            va[u * 4 + 0] = f.x; va[u * 4 + 1] = f.y;
            va[u * 4 + 2] = f.z; va[u * 4 + 3] = f.w;
        }
#pragma unroll
        for (int j2 = 0; j2 < 2; ++j2) {
            us8 h;
#pragma unroll
            for (int j = 0; j < 8; ++j) h[j] = f2bf(va[j2 * 8 + j]);
            int cc = cq * 2 + j2;
            *(us8*)&sm.s.A[r * 64 + (cc ^ (r & 7)) * 8] = h;
        }
#pragma unroll
        for (int u = 0; u < 4; ++u) {
            float4 f = *(const float4*)&Bsrc[(size_t)(kt * 64 + r) * 512 + n0 + cq * 16 + u * 4];
            float vv[4] = {f.x, f.y, f.z, f.w};
#pragma unroll
            for (int j = 0; j < 4; ++j) {
                int n = cq * 16 + u * 4 + j;
                sm.s.B[n * 64 + ((r >> 3) ^ (n & 7)) * 8 + (r & 7)] = f2bf(vv[j]);
            }
        }
        __syncthreads();
        MFMA_STEP(acc)
        __syncthreads();
    }
    ACC_TO_EPI(acc)
}

__device__ inline void epi_out_bf(unsigned short* __restrict__ dst, int m0,
                                  int n0, int t, SqSmem& sm) {
    const int r = t >> 2, cq = t & 3;
    us8 h0, h1;
#pragma unroll
    for (int j = 0; j < 8; ++j) {
        h0[j] = f2bf(sm.epi[r * 68 + cq * 16 + j]);
        h1[j] = f2bf(sm.epi[r * 68 + cq * 16 + 8 + j]);
    }
    *(us8*)&dst[(size_t)(m0 + r) * 512 + n0 + cq * 16]     = h0;
    *(us8*)&dst[(size_t)(m0 + r) * 512 + n0 + cq * 16 + 8] = h1;
}
__device__ inline void epi_out_bfT(unsigned short* __restrict__ dst, int m0,
                                   int n0, int t, SqSmem& sm) {
    const int cf = t >> 2, rq = t & 3;
    us8 o0, o1;
#pragma unroll
    for (int i = 0; i < 8; ++i) {
        o0[i] = f2bf(sm.epi[(rq * 16 + i) * 68 + cf]);
        o1[i] = f2bf(sm.epi[(rq * 16 + 8 + i) * 68 + cf]);
    }
    *(us8*)&dst[(size_t)(n0 + cf) * 512 + m0 + rq * 16]     = o0;
    *(us8*)&dst[(size_t)(n0 + cf) * 512 + m0 + rq * 16 + 8] = o1;
}

// ===========================================================================
// k_s1 (grid 384): x->bf16; y=b2; 0..63: A2 = f32src(A,A); 64..127: AT_bf;
// 128..383: U1 = f32src(W1,A)    (r7/r11-proven)
// ===========================================================================
__global__ __launch_bounds__(256) void k_s1(
    const float* __restrict__ A, const float* __restrict__ x,
    const float* __restrict__ W1, const float* __restrict__ b2,
    unsigned short* __restrict__ A2_bf, unsigned short* __restrict__ A2T_bf,
    unsigned short* __restrict__ AT_bf, unsigned short* __restrict__ U1_bf,
    unsigned short* __restrict__ x_bf, float* __restrict__ y) {
    __shared__ SqSmem sm;
    const int b = blockIdx.x, t = threadIdx.x;
    const int gid = b * 256 + t;                 // 0 .. 98303

    const float4* x4 = (const float4*)x;
#pragma unroll
    for (int i = 0; i < 3; ++i) {
        int id = gid + i * 98304;
        if (id < 262144) {
            float4 v0 = x4[(size_t)id * 2], v1 = x4[(size_t)id * 2 + 1];
            us8 o;
            o[0] = f2bf(v0.x); o[1] = f2bf(v0.y); o[2] = f2bf(v0.z); o[3] = f2bf(v0.w);
            o[4] = f2bf(v1.x); o[5] = f2bf(v1.y); o[6] = f2bf(v1.z); o[7] = f2bf(v1.w);
            *(us8*)&x_bf[(size_t)id * 8] = o;
        }
    }
    if (gid < B_SZ * DY) y[gid] = b2[gid % 10];

    if (b < 64) {
        const int m0 = (b >> 3) * 64, n0 = (b & 7) * 64;
        gemm64_f32src(A, A, m0, n0, t, sm);
        epi_out_bf(A2_bf, m0, n0, t, sm);
        epi_out_bfT(A2T_bf, m0, n0, t, sm);
    } else if (b < 128) {
        const int bb = b - 64, m0 = (bb >> 3) * 64, n0 = (bb & 7) * 64;
        const int r = t >> 2, cq = t & 3;
#pragma unroll
        for (int u = 0; u < 4; ++u) {
            float4 f = *(const float4*)&A[(size_t)(m0 + r) * 512 + n0 + cq * 16 + u * 4];
            sm.epi[r * 68 + cq * 16 + u * 4 + 0] = f.x;
            sm.epi[r * 68 + cq * 16 + u * 4 + 1] = f.y;
            sm.epi[r * 68 + cq * 16 + u * 4 + 2] = f.z;
            sm.epi[r * 68 + cq * 16 + u * 4 + 3] = f.w;
        }
        __syncthreads();
        epi_out_bfT(AT_bf, m0, n0, t, sm);
    } else {
        const int bb = b - 128, m0 = (bb >> 3) * 64, n0 = (bb & 7) * 64;
        gemm64_f32src(W1, A, m0, n0, t, sm);     // U1 = W1·A
        epi_out_bf(U1_bf, m0, n0, t, sm);
    }
}

// ===========================================================================
// k_s2 (grid 576): 0..63: A3 = A2·A -> A3T_bf ; 64..319: U2 = U1·A ;
// 320..575: U3 = U1·A2    (r7/r11-proven)
// ===========================================================================
__global__ __launch_bounds__(256) void k_s2(
    const unsigned short* __restrict__ A2_bf,
    const unsigned short* __restrict__ A2T_bf,
    const unsigned short* __restrict__ AT_bf,
    const unsigned short* __restrict__ U1_bf,
    unsigned short* __restrict__ A3T_bf, unsigned short* __restrict__ U2_bf,
    unsigned short* __restrict__ U3_bf) {
    __shared__ SqSmem sm;
    const int b = blockIdx.x, t = threadIdx.x;
    if (b < 64) {
        const int m0 = (b >> 3) * 64, n0 = (b & 7) * 64;
        gemm64_mfma(A2_bf, AT_bf, m0, n0, t, sm);
        epi_out_bfT(A3T_bf, m0, n0, t, sm);
    } else if (b < 320) {
        const int bb = b - 64, m0 = (bb >> 3) * 64, n0 = (bb & 7) * 64;
        gemm64_mfma(U1_bf, AT_bf, m0, n0, t, sm);
        epi_out_bf(U2_bf, m0, n0, t, sm);
    } else {
        const int bb = b - 320, m0 = (bb >> 3) * 64, n0 = (bb & 7) * 64;
        gemm64_mfma(U1_bf, A2T_bf, m0, n0, t, sm);
        epi_out_bf(U3_bf, m0, n0, t, sm);
    }
}

// ===========================================================================
// k_s3 (grid 256): w1f = bf16( W1 + U1 + c2U2 + c3U3
//                              + (c4U1 + c5U2 + c6U3)·A3 )   (r7/r11-proven)
// ===========================================================================
__global__ __launch_bounds__(256) void k_s3(
    const float* __restrict__ W1, const unsigned short* __restrict__ U1_bf,
    const unsigned short* __restrict__ U2_bf,
    const unsigned short* __restrict__ U3_bf,
    const unsigned short* __restrict__ A3T_bf,
    unsigned short* __restrict__ w1f) {
    __shared__ SqSmem sm;
    const int b = blockIdx.x, t = threadIdx.x;
    const int m0 = (b >> 3) * 64, n0 = (b & 7) * 64;
    const int lane = t & 63, w = t >> 6, quad = lane >> 4, l16 = lane & 15;
    const int wm = (w & 1) * 32, wn = (w >> 1) * 32;
    f32x4 acc[2][2];
#pragma unroll
    for (int i = 0; i < 2; ++i)
#pragma unroll
        for (int j = 0; j < 2; ++j) acc[i][j] = (f32x4){0.f, 0.f, 0.f, 0.f};
    for (int kt = 0; kt < 8; ++kt) {
#pragma unroll
        for (int c = 0; c < 2; ++c) {
            int idx = c * 256 + t, row = idx >> 3, cc = idx & 7;
            int ccs = cc ^ (row & 7);
            size_t ga = (size_t)(m0 + row) * 512 + kt * 64 + cc * 8;
            us8 u1 = *(const us8*)&U1_bf[ga];
            us8 u2 = *(const us8*)&U2_bf[ga];
            us8 u3 = *(const us8*)&U3_bf[ga];
            us8 g;
#pragma unroll
            for (int j = 0; j < 8; ++j)
                g[j] = f2bf(C4 * bf2f(u1[j]) + C5 * bf2f(u2[j]) + C6 * bf2f(u3[j]));
            *(us8*)&sm.s.A[row * 64 + ccs * 8] = g;
            *(us8*)&sm.s.B[row * 64 + ccs * 8] =
                *(const us8*)&A3T_bf[(size_t)(n0 + row) * 512 + kt * 64 + cc * 8];
        }
        __syncthreads();
        MFMA_STEP(acc)
        __syncthreads();
    }
    ACC_TO_EPI(acc)
    const int r = t >> 2, cq = t & 3;
    size_t gbase = (size_t)(m0 + r) * 512 + n0 + cq * 16;
    us8 u1a = *(const us8*)&U1_bf[gbase], u1b = *(const us8*)&U1_bf[gbase + 8];
    us8 u2a = *(const us8*)&U2_bf[gbase], u2b = *(const us8*)&U2_bf[gbase + 8];
    us8 u3a = *(const us8*)&U3_bf[gbase], u3b = *(const us8*)&U3_bf[gbase + 8];
    us8 h0, h1;
#pragma unroll
    for (int u = 0; u < 2; ++u) {
        float4 wv = *(const float4*)&W1[gbase + u * 4];
        float4 wv2 = *(const float4*)&W1[gbase + 8 + u * 4];
#pragma unroll
        for (int j = 0; j < 4; ++j) {
            int e = u * 4 + j;
            float wj = (j == 0 ? wv.x : j == 1 ? wv.y : j == 2 ? wv.z : wv.w);
            float wj2 = (j == 0 ? wv2.x : j == 1 ? wv2.y : j == 2 ? wv2.z : wv2.w);
            h0[e] = f2bf(wj + bf2f(u1a[e]) + C2 * bf2f(u2a[e]) +
                         C3 * bf2f(u3a[e]) + sm.epi[r * 68 + cq * 16 + e]);
            h1[e] = f2bf(wj2 + bf2f(u1b[e]) + C2 * bf2f(u2b[e]) +
                         C3 * bf2f(u3b[e]) + sm.epi[r * 68 + cq * 16 + 8 + e]);
        }
    }
    *(us8*)&w1f[gbase]     = h0;
    *(us8*)&w1f[gbase + 8] = h1;
}

// ===========================================================================
// mlp v7: 64x128 (m x n) tiles, grid (64,16) = 1024 blocks (4/CU), staging
// 24 KB. Same K-loop discipline as proven r11 (single-buffer, 2 barriers),
// same MFMA epilogue, same total atomic count (655K).
// ===========================================================================
union SmemU {
    struct { unsigned short A[64 * 64]; unsigned short B[128 * 64]; } s; // 24 KB
    struct { unsigned short h[64 * 136]; } e;                            // 17.4 KB
};

__global__ __launch_bounds__(256) void mlp_kernel(
    const unsigned short* __restrict__ x_bf,
    const unsigned short* __restrict__ w1f,
    const float* __restrict__ b1, const float* __restrict__ W2,
    float* __restrict__ y) {
    __shared__ SmemU sm;
    const int t    = threadIdx.x;
    const int lane = t & 63, w = t >> 6;
    const int quad = lane >> 4, l16 = lane & 15;
    const int wn = w * 32;                       // wave owns n-slice [wn, wn+32)
    const int m0g = blockIdx.x * 64, n0g = blockIdx.y * 128;

    f32x4 acc[4][2];
#pragma unroll
    for (int i = 0; i < 4; ++i)
#pragma unroll
        for (int j = 0; j < 2; ++j) acc[i][j] = (f32x4){0.f, 0.f, 0.f, 0.f};

    for (int kt = 0; kt < 8; ++kt) {
        // A tile: 64x64 (512 chunks)
#pragma unroll
        for (int c = 0; c < 2; ++c) {
            int idx = c * 256 + t, row = idx >> 3, cc = idx & 7;
            int ccs = cc ^ (row & 7);
            *(us8*)&sm.s.A[row * 64 + ccs * 8] =
                *(const us8*)&x_bf[(size_t)(m0g + row) * 512 + kt * 64 + cc * 8];
        }
        // B tile: 128x64 (1024 chunks)
#pragma unroll
        for (int c = 0; c < 4; ++c) {
            int idx = c * 256 + t, row = idx >> 3, cc = idx & 7;
            int ccs = cc ^ (row & 7);
            *(us8*)&sm.s.B[row * 64 + ccs * 8] =
                *(const us8*)&w1f[(size_t)(n0g + row) * 512 + kt * 64 + cc * 8];
        }
        __syncthreads();
#pragma unroll
        for (int ks = 0; ks < 2; ++ks) {
            bf16x8 af[4], bfr[2];
#pragma unroll
            for (int i = 0; i < 4; ++i) {
                int ra = i * 16 + l16, ca = (ks * 4 + quad) ^ (ra & 7);
                af[i] = *(const bf16x8*)&sm.s.A[ra * 64 + ca * 8];
            }
#pragma unroll
            for (int j = 0; j < 2; ++j) {
                int rb = wn + j * 16 + l16, cb = (ks * 4 + quad) ^ (rb & 7);
                bfr[j] = *(const bf16x8*)&sm.s.B[rb * 64 + cb * 8];
            }
#pragma unroll
            for (int i = 0; i < 4; ++i)
#pragma unroll
                for (int j = 0; j < 2; ++j)
                    acc[i][j] = __builtin_amdgcn_mfma_f32_16x16x32_bf16(
                        af[i], bfr[j], acc[i][j], 0, 0, 0);
        }
        __syncthreads();
    }

    // ---- epilogue: bias + relu -> LDS h (m-major, stride 136, 16B rows) ----
    float bias[2];
#pragma unroll
    for (int j = 0; j < 2; ++j) bias[j] = b1[n0g + wn + j * 16 + l16];
#pragma unroll
    for (int i = 0; i < 4; ++i)
#pragma unroll
        for (int j = 0; j < 2; ++j)
#pragma unroll
            for (int r = 0; r < 4; ++r) {
                float h = acc[i][j][r] + bias[j];
                h = h > 0.f ? h : 0.f;
                sm.e.h[(i * 16 + quad * 4 + r) * 136 + wn + j * 16 + l16] = f2bf(h);
            }
    __syncthreads();

    // ---- y += h @ W2^T via MFMA: wave w owns m-rows [w*16, w*16+16) ----
    {
        bf16x8 wfrag[4];
#pragma unroll
        for (int kc = 0; kc < 4; ++kc) {
            us8 wb;
            if (l16 < DY) {
                const float* wp = &W2[(size_t)l16 * H_SZ + n0g + kc * 32 + quad * 8];
#pragma unroll
                for (int j = 0; j < 8; ++j) wb[j] = f2bf(wp[j]);
            } else {
#pragma unroll
                for (int j = 0; j < 8; ++j) wb[j] = 0;
            }
            wfrag[kc] = *(bf16x8*)&wb;
        }
        f32x4 ay = (f32x4){0.f, 0.f, 0.f, 0.f};
        const int mrow = w * 16;
#pragma unroll
        for (int kc = 0; kc < 4; ++kc) {
            bf16x8 af = *(const bf16x8*)&sm.e.h[(mrow + l16) * 136 + kc * 32 + quad * 8];
            ay = __builtin_amdgcn_mfma_f32_16x16x32_bf16(af, wfrag[kc], ay, 0, 0, 0);
        }
        if (l16 < DY) {
#pragma unroll
            for (int r = 0; r < 4; ++r)
                atomicAdd(&y[(size_t)(m0g + mrow + quad * 4 + r) * DY + l16],
                          ay[r]);
        }
    }
}

// ===========================================================================
extern "C" void kernel_launch(void* const* d_in, const int* in_sizes, int n_in,
                              void* d_out, int out_size, void* d_ws, size_t ws_size,
                              hipStream_t stream) {
    const float* x  = (const float*)d_in[0];
    const float* A  = (const float*)d_in[1];
    const float* W1 = (const float*)d_in[2];
    const float* b1 = (const float*)d_in[3];
    const float* W2 = (const float*)d_in[4];
    const float* b2 = (const float*)d_in[5];
    float* y = (float*)d_out;

    char* ws = (char*)d_ws;
    const size_t HMB = 512u * 1024, MB = 1u << 20;
    unsigned short* AT_bf  = (unsigned short*)(ws);
    unsigned short* A2_bf  = (unsigned short*)(ws + 1 * HMB);
    unsigned short* A2T_bf = (unsigned short*)(ws + 2 * HMB);
    unsigned short* A3T_bf = (unsigned short*)(ws + 3 * HMB);
    unsigned short* U1_bf  = (unsigned short*)(ws + 2 * MB);   // 2 MB
    unsigned short* U2_bf  = (unsigned short*)(ws + 4 * MB);   // 2 MB
    unsigned short* U3_bf  = (unsigned short*)(ws + 6 * MB);   // 2 MB
    unsigned short* w1f    = (unsigned short*)(ws + 8 * MB);   // 2 MB
    unsigned short* x_bf   = (unsigned short*)(ws + 10 * MB);  // 4 MB

    k_s1<<<384, 256, 0, stream>>>(A, x, W1, b2, A2_bf, A2T_bf, AT_bf, U1_bf,
                                  x_bf, y);
    k_s2<<<576, 256, 0, stream>>>(A2_bf, A2T_bf, AT_bf, U1_bf, A3T_bf, U2_bf,
                                  U3_bf);
    k_s3<<<256, 256, 0, stream>>>(W1, U1_bf, U2_bf, U3_bf, A3T_bf, w1f);
    mlp_kernel<<<dim3(64, 16), dim3(256), 0, stream>>>(x_bf, w1f, b1, W2, y);
}